// Round 1
// baseline (162.799 us; speedup 1.0000x reference)
//
#include <hip/hip_runtime.h>

// B=16, Q=256, K=256, H=256, DV=256
#define Bn 16
#define Qn 256
#define Kn 256
#define Hn 256
#define DVn 256

constexpr float C2    = 2.8853900817779268f;   // 2/ln2  : e^{2x} = 2^{C2*x}
constexpr float LOG2E = 1.4426950408889634f;

__device__ __forceinline__ float fast_exp2(float x) { return __builtin_amdgcn_exp2f(x); }
__device__ __forceinline__ float fast_rcp(float x)  { return __builtin_amdgcn_rcpf(x); }

// ------------------------------------------------------------------
// K1: E = exp(2 * (X @ W^T))   [rows 4096 = B*256, cols 256]
// z=0 -> queries/W_q/Eq ; z=1 -> keys/W_k/Ek
// 64x64 tile, BK=16, 256 threads, 4x4 micro-tile
// ------------------------------------------------------------------
__global__ __launch_bounds__(256)
void proj_exp_kernel(const float* __restrict__ Xq, const float* __restrict__ Xk,
                     const float* __restrict__ Wq, const float* __restrict__ Wk,
                     float* __restrict__ Eq, float* __restrict__ Ek)
{
    const float* X = blockIdx.z ? Xk : Xq;
    const float* W = blockIdx.z ? Wk : Wq;
    float*       E = blockIdx.z ? Ek : Eq;
    const int m0 = blockIdx.y * 64;
    const int n0 = blockIdx.x * 64;
    __shared__ float As[16][68];   // [k][m], pitch 68 keeps float4 reads 16B-aligned
    __shared__ float Bs[16][68];   // [k][n]
    const int tid = threadIdx.x;
    const int tx = tid & 15, ty = tid >> 4;
    const int lr = tid >> 2, lk4 = (tid & 3) * 4;
    float acc[4][4] = {};
    for (int k0 = 0; k0 < Hn; k0 += 16) {
        float4 a = *(const float4*)(X + (size_t)(m0 + lr) * Hn + k0 + lk4);
        float4 w = *(const float4*)(W + (size_t)(n0 + lr) * Hn + k0 + lk4);
        As[lk4+0][lr] = a.x; As[lk4+1][lr] = a.y; As[lk4+2][lr] = a.z; As[lk4+3][lr] = a.w;
        Bs[lk4+0][lr] = w.x; Bs[lk4+1][lr] = w.y; Bs[lk4+2][lr] = w.z; Bs[lk4+3][lr] = w.w;
        __syncthreads();
        #pragma unroll
        for (int kk = 0; kk < 16; ++kk) {
            float4 av = *(const float4*)&As[kk][ty*4];
            float4 bv = *(const float4*)&Bs[kk][tx*4];
            const float ar[4] = {av.x, av.y, av.z, av.w};
            const float br[4] = {bv.x, bv.y, bv.z, bv.w};
            #pragma unroll
            for (int i = 0; i < 4; ++i)
                #pragma unroll
                for (int j = 0; j < 4; ++j)
                    acc[i][j] = fmaf(ar[i], br[j], acc[i][j]);
        }
        __syncthreads();
    }
    #pragma unroll
    for (int i = 0; i < 4; ++i) {
        float4 o;
        o.x = fast_exp2(C2 * acc[i][0]);
        o.y = fast_exp2(C2 * acc[i][1]);
        o.z = fast_exp2(C2 * acc[i][2]);
        o.w = fast_exp2(C2 * acc[i][3]);
        *(float4*)(E + (size_t)(m0 + ty*4 + i) * Hn + n0 + tx*4) = o;
    }
}

// ------------------------------------------------------------------
// K2: scores + softmax -> attn
//   score(q,k) ~ -2 * sum_h w_v[h] * rcp(1 + Eq[q,h]*Ek[k,h])   (shift-invariant)
// grid (Q/16, B); block 256; q-tile 16; k staged in 4 tiles of 64;
// each thread owns a 2q x 2k micro-tile.
// ------------------------------------------------------------------
__global__ __launch_bounds__(256)
void attn_scores_kernel(const float* __restrict__ Eq, const float* __restrict__ Ek,
                        const float* __restrict__ wv, float* __restrict__ attn)
{
    const int qt = blockIdx.x;   // 0..15
    const int b  = blockIdx.y;   // 0..15
    __shared__ float sEq[16][257];   // pitch 257: scalar reads land on distinct banks
    __shared__ float sEk[64][257];
    __shared__ float sS[16][260];
    __shared__ float swv[256];
    __shared__ float srow[16];
    const int tid = threadIdx.x;
    swv[tid] = wv[tid];
    for (int i = tid; i < 16*64; i += 256) {
        const int q = i >> 6, h4 = (i & 63) * 4;
        float4 v = *(const float4*)(Eq + ((size_t)(b*Qn + qt*16 + q)) * Hn + h4);
        sEq[q][h4+0] = v.x; sEq[q][h4+1] = v.y; sEq[q][h4+2] = v.z; sEq[q][h4+3] = v.w;
    }
    const int qg = tid >> 5, kg = tid & 31;
    const int q0 = qg * 2, k0l = kg * 2;
    for (int kt = 0; kt < 4; ++kt) {
        __syncthreads();   // protect sEk reuse (also covers sEq/swv on first pass)
        for (int i = tid; i < 64*64; i += 256) {
            const int k = i >> 6, h4 = (i & 63) * 4;
            float4 v = *(const float4*)(Ek + ((size_t)(b*Kn + kt*64 + k)) * Hn + h4);
            sEk[k][h4+0] = v.x; sEk[k][h4+1] = v.y; sEk[k][h4+2] = v.z; sEk[k][h4+3] = v.w;
        }
        __syncthreads();
        float a00 = 0.f, a01 = 0.f, a10 = 0.f, a11 = 0.f;
        #pragma unroll 4
        for (int h = 0; h < Hn; ++h) {
            const float w   = swv[h];
            const float eq0 = sEq[q0  ][h], eq1 = sEq[q0+1 ][h];
            const float ek0 = sEk[k0l ][h], ek1 = sEk[k0l+1][h];
            a00 = fmaf(w, fast_rcp(fmaf(eq0, ek0, 1.0f)), a00);
            a01 = fmaf(w, fast_rcp(fmaf(eq0, ek1, 1.0f)), a01);
            a10 = fmaf(w, fast_rcp(fmaf(eq1, ek0, 1.0f)), a10);
            a11 = fmaf(w, fast_rcp(fmaf(eq1, ek1, 1.0f)), a11);
        }
        sS[q0+0][kt*64 + k0l+0] = a00;
        sS[q0+0][kt*64 + k0l+1] = a01;
        sS[q0+1][kt*64 + k0l+0] = a10;
        sS[q0+1][kt*64 + k0l+1] = a11;
    }
    __syncthreads();
    // row-wise softmax over k: 16 lanes per q-row
    const int q = tid >> 4, j = tid & 15;
    float mx = -1e30f;
    for (int k = j; k < Kn; k += 16) mx = fmaxf(mx, -2.0f * sS[q][k]);
    #pragma unroll
    for (int off = 1; off < 16; off <<= 1) mx = fmaxf(mx, __shfl_xor(mx, off, 64));
    float ssum = 0.f;
    for (int k = j; k < Kn; k += 16) {
        const float p = fast_exp2(LOG2E * (-2.0f * sS[q][k] - mx));
        sS[q][k] = p;
        ssum += p;
    }
    #pragma unroll
    for (int off = 1; off < 16; off <<= 1) ssum += __shfl_xor(ssum, off, 64);
    if (j == 0) srow[q] = fast_rcp(ssum);
    __syncthreads();
    float* ab = attn + ((size_t)(b*Qn + qt*16)) * Kn;
    #pragma unroll
    for (int i = 0; i < 16; ++i)
        ab[(size_t)i * Kn + tid] = sS[i][tid] * srow[i];
}

// ------------------------------------------------------------------
// K3: out[b] = attn[b] @ V[b]   (256x256 @ 256x256 per b)
// ------------------------------------------------------------------
__global__ __launch_bounds__(256)
void pv_kernel(const float* __restrict__ attn, const float* __restrict__ V,
               float* __restrict__ out)
{
    const int b  = blockIdx.z;
    const int m0 = blockIdx.y * 64, n0 = blockIdx.x * 64;
    __shared__ float As[16][68];   // [k][m]
    __shared__ float Bs[16][68];   // [k][n]
    const float* Ab = attn + (size_t)b * Qn * Kn;
    const float* Vb = V    + (size_t)b * Kn * DVn;
    const int tid = threadIdx.x;
    const int tx = tid & 15, ty = tid >> 4;
    const int lr = tid >> 2, lk4 = (tid & 3) * 4;
    float acc[4][4] = {};
    for (int k0 = 0; k0 < Kn; k0 += 16) {
        float4 a = *(const float4*)(Ab + (size_t)(m0 + lr) * Kn + k0 + lk4);
        As[lk4+0][lr] = a.x; As[lk4+1][lr] = a.y; As[lk4+2][lr] = a.z; As[lk4+3][lr] = a.w;
        float4 v = *(const float4*)(Vb + (size_t)(k0 + ty) * DVn + n0 + tx*4);
        *(float4*)&Bs[ty][tx*4] = v;   // pitch 68 -> 16B-aligned b128 write
        __syncthreads();
        #pragma unroll
        for (int kk = 0; kk < 16; ++kk) {
            float4 av = *(const float4*)&As[kk][ty*4];
            float4 bv = *(const float4*)&Bs[kk][tx*4];
            const float ar[4] = {av.x, av.y, av.z, av.w};
            const float br[4] = {bv.x, bv.y, bv.z, bv.w};
            #pragma unroll
            for (int i = 0; i < 4; ++i)
                #pragma unroll
                for (int j = 0; j < 4; ++j)
                    acc[i][j] = fmaf(ar[i], br[j], acc[i][j]);
        }
        __syncthreads();
    }
    #pragma unroll
    for (int i = 0; i < 4; ++i)
        *(float4*)(out + ((size_t)(b*Qn + m0 + ty*4 + i)) * DVn + n0 + tx*4) =
            make_float4(acc[i][0], acc[i][1], acc[i][2], acc[i][3]);
}

extern "C" void kernel_launch(void* const* d_in, const int* in_sizes, int n_in,
                              void* d_out, int out_size, void* d_ws, size_t ws_size,
                              hipStream_t stream) {
    const float* queries = (const float*)d_in[0];  // [16,256,256]
    const float* keys    = (const float*)d_in[1];  // [16,256,256]
    const float* values  = (const float*)d_in[2];  // [16,256,256]
    const float* W_q     = (const float*)d_in[3];  // [256,256]
    const float* W_k     = (const float*)d_in[4];  // [256,256]
    const float* w_v     = (const float*)d_in[5];  // [256]
    float* out = (float*)d_out;

    // workspace layout: Eq (4 MB) | Ek (4 MB) | attn (4 MB)
    float* Eq   = (float*)d_ws;
    float* Ek   = Eq + (size_t)Bn * Qn * Hn;
    float* attn = Ek + (size_t)Bn * Kn * Hn;

    proj_exp_kernel<<<dim3(4, 64, 2), 256, 0, stream>>>(queries, keys, W_q, W_k, Eq, Ek);
    attn_scores_kernel<<<dim3(16, 16), 256, 0, stream>>>(Eq, Ek, w_v, attn);
    pv_kernel<<<dim3(4, 4, 16), 256, 0, stream>>>(attn, values, out);
}

// Round 2
// 149.694 us; speedup vs baseline: 1.0875x; 1.0875x over previous
//
#include <hip/hip_runtime.h>

// B=16, Q=256, K=256, H=256, DV=256
#define Bn 16
#define Qn 256
#define Kn 256
#define Hn 256
#define DVn 256

constexpr float C2    = 2.8853900817779268f;   // 2/ln2 : e^{2x} = 2^(C2*x)
constexpr float LOG2E = 1.4426950408889634f;

__device__ __forceinline__ float fast_exp2(float x) { return __builtin_amdgcn_exp2f(x); }
__device__ __forceinline__ float fast_rcp(float x)  { return __builtin_amdgcn_rcpf(x); }

// ------------------------------------------------------------------
// K1: C[M][N] = exp2(C2 * (A[M][256] @ B[N][256]^T))
//   launch A=queries,B=W_q -> Eq[4096][256]   (grid  4,64)
//   launch A=W_k,B=keys    -> EkT[256][4096]  (grid 64, 4)   (= W_k @ keys^T)
// 64x64 tile, BK=16, 256 threads, 4x4 micro-tile
// ------------------------------------------------------------------
__global__ __launch_bounds__(256)
void proj_exp_kernel(const float* __restrict__ A, const float* __restrict__ Bm,
                     float* __restrict__ C, int N)
{
    const int m0 = blockIdx.y * 64;
    const int n0 = blockIdx.x * 64;
    __shared__ __align__(16) float As[16][68];   // [k][m]
    __shared__ __align__(16) float Bs[16][68];   // [k][n]
    const int tid = threadIdx.x;
    const int tx = tid & 15, ty = tid >> 4;
    const int lr = tid >> 2, lk4 = (tid & 3) * 4;
    float acc[4][4] = {};
    for (int k0 = 0; k0 < Hn; k0 += 16) {
        float4 a = *(const float4*)(A  + (size_t)(m0 + lr) * Hn + k0 + lk4);
        float4 w = *(const float4*)(Bm + (size_t)(n0 + lr) * Hn + k0 + lk4);
        As[lk4+0][lr] = a.x; As[lk4+1][lr] = a.y; As[lk4+2][lr] = a.z; As[lk4+3][lr] = a.w;
        Bs[lk4+0][lr] = w.x; Bs[lk4+1][lr] = w.y; Bs[lk4+2][lr] = w.z; Bs[lk4+3][lr] = w.w;
        __syncthreads();
        #pragma unroll
        for (int kk = 0; kk < 16; ++kk) {
            float4 av = *(const float4*)&As[kk][ty*4];
            float4 bv = *(const float4*)&Bs[kk][tx*4];
            const float ar[4] = {av.x, av.y, av.z, av.w};
            const float br[4] = {bv.x, bv.y, bv.z, bv.w};
            #pragma unroll
            for (int i = 0; i < 4; ++i)
                #pragma unroll
                for (int j = 0; j < 4; ++j)
                    acc[i][j] = fmaf(ar[i], br[j], acc[i][j]);
        }
        __syncthreads();
    }
    #pragma unroll
    for (int i = 0; i < 4; ++i) {
        float4 o;
        o.x = fast_exp2(C2 * acc[i][0]);
        o.y = fast_exp2(C2 * acc[i][1]);
        o.z = fast_exp2(C2 * acc[i][2]);
        o.w = fast_exp2(C2 * acc[i][3]);
        *(float4*)(C + (size_t)(m0 + ty*4 + i) * N + n0 + tx*4) = o;
    }
}

// ------------------------------------------------------------------
// K2 fused: scores + softmax + PV -> out
// grid (Q/4=64, B=16), block 256. Thread t owns k-column t for 4 q-rows.
//   score(q,k) = -2 * sum_h wv[h] * rcp(1 + Eq[q,h]*EkT[h,k])  (softmax shift-inv)
// ek: coalesced global b32 (EkT lane-stride 1, L2 resident)
// eq/wv: LDS same-address broadcast b128 (free)
// then softmax (wave shuffle + tiny LDS cross-wave), then PV with p in LDS.
// ------------------------------------------------------------------
__global__ __launch_bounds__(256)
void fused_attn_kernel(const float* __restrict__ Eq, const float* __restrict__ EkT,
                       const float* __restrict__ wv, const float* __restrict__ V,
                       float* __restrict__ out)
{
    const int b  = blockIdx.y;
    const int q0 = blockIdx.x * 4;
    __shared__ __align__(16) float sEq[4 * 256];
    __shared__ __align__(16) float swv[256];
    __shared__ __align__(16) float sP[4 * 260];
    __shared__ float sredM[4][4];
    __shared__ float sredS[4][4];
    const int tid = threadIdx.x;
    {
        const int q = tid >> 6, h4 = (tid & 63) * 4;
        float4 v = *(const float4*)(Eq + (size_t)(b*Qn + q0 + q) * Hn + h4);
        *(float4*)&sEq[q*256 + h4] = v;
        swv[tid] = wv[tid];
    }
    __syncthreads();

    float sc[4] = {0.f, 0.f, 0.f, 0.f};
    const float* ekp = EkT + (size_t)b * Kn + tid;   // row stride Bn*Kn = 4096
    for (int h0 = 0; h0 < Hn; h0 += 8) {
        float ek[8];
        #pragma unroll
        for (int j = 0; j < 8; ++j) ek[j] = ekp[(size_t)(h0 + j) * (Bn * Kn)];
        const float4 wa = *(const float4*)&swv[h0];
        const float4 wb = *(const float4*)&swv[h0 + 4];
        #pragma unroll
        for (int q = 0; q < 4; ++q) {
            const float4 ea = *(const float4*)&sEq[q*256 + h0];
            const float4 eb = *(const float4*)&sEq[q*256 + h0 + 4];
            float a = sc[q];
            a = fmaf(wa.x, fast_rcp(fmaf(ea.x, ek[0], 1.f)), a);
            a = fmaf(wa.y, fast_rcp(fmaf(ea.y, ek[1], 1.f)), a);
            a = fmaf(wa.z, fast_rcp(fmaf(ea.z, ek[2], 1.f)), a);
            a = fmaf(wa.w, fast_rcp(fmaf(ea.w, ek[3], 1.f)), a);
            a = fmaf(wb.x, fast_rcp(fmaf(eb.x, ek[4], 1.f)), a);
            a = fmaf(wb.y, fast_rcp(fmaf(eb.y, ek[5], 1.f)), a);
            a = fmaf(wb.z, fast_rcp(fmaf(eb.z, ek[6], 1.f)), a);
            a = fmaf(wb.w, fast_rcp(fmaf(eb.w, ek[7], 1.f)), a);
            sc[q] = a;
        }
    }

    // ---- softmax over k (scores = -2*sc), per-wave shuffle + cross-wave LDS ----
    const int w = tid >> 6, lane = tid & 63;
    #pragma unroll
    for (int q = 0; q < 4; ++q) {
        sc[q] = -2.0f * sc[q];
        float mx = sc[q];
        #pragma unroll
        for (int off = 32; off; off >>= 1) mx = fmaxf(mx, __shfl_xor(mx, off, 64));
        if (lane == 0) sredM[q][w] = mx;
    }
    __syncthreads();
    float p[4];
    #pragma unroll
    for (int q = 0; q < 4; ++q) {
        const float mx = fmaxf(fmaxf(sredM[q][0], sredM[q][1]),
                               fmaxf(sredM[q][2], sredM[q][3]));
        p[q] = fast_exp2(LOG2E * (sc[q] - mx));
        float s = p[q];
        #pragma unroll
        for (int off = 32; off; off >>= 1) s += __shfl_xor(s, off, 64);
        if (lane == 0) sredS[q][w] = s;
        sP[q*260 + tid] = p[q];
    }
    __syncthreads();
    float rinv[4];
    #pragma unroll
    for (int q = 0; q < 4; ++q)
        rinv[q] = fast_rcp(sredS[q][0] + sredS[q][1] + sredS[q][2] + sredS[q][3]);

    // ---- PV: thread owns dv = tid, all 4 q; p via LDS broadcast b128 ----
    float acc[4] = {0.f, 0.f, 0.f, 0.f};
    const float* Vb = V + (size_t)b * Kn * DVn + tid;
    for (int k = 0; k < Kn; k += 4) {
        float vv[4];
        #pragma unroll
        for (int j = 0; j < 4; ++j) vv[j] = Vb[(size_t)(k + j) * DVn];
        #pragma unroll
        for (int q = 0; q < 4; ++q) {
            const float4 pq = *(const float4*)&sP[q*260 + k];
            float a = acc[q];
            a = fmaf(pq.x, vv[0], a);
            a = fmaf(pq.y, vv[1], a);
            a = fmaf(pq.z, vv[2], a);
            a = fmaf(pq.w, vv[3], a);
            acc[q] = a;
        }
    }
    float* ob = out + (size_t)(b*Qn + q0) * DVn + tid;
    #pragma unroll
    for (int q = 0; q < 4; ++q)
        ob[(size_t)q * DVn] = acc[q] * rinv[q];
}

extern "C" void kernel_launch(void* const* d_in, const int* in_sizes, int n_in,
                              void* d_out, int out_size, void* d_ws, size_t ws_size,
                              hipStream_t stream) {
    const float* queries = (const float*)d_in[0];  // [16,256,256]
    const float* keys    = (const float*)d_in[1];  // [16,256,256]
    const float* values  = (const float*)d_in[2];  // [16,256,256]
    const float* W_q     = (const float*)d_in[3];  // [256,256]
    const float* W_k     = (const float*)d_in[4];  // [256,256]
    const float* w_v     = (const float*)d_in[5];  // [256]
    float* out = (float*)d_out;

    // workspace: Eq [4096][256] (4MB) | EkT [256][4096] (4MB)
    float* Eq  = (float*)d_ws;
    float* EkT = Eq + (size_t)Bn * Qn * Hn;

    // Eq = exp(2*(queries @ W_q^T)) : M=4096, N=256
    proj_exp_kernel<<<dim3(4, 64), 256, 0, stream>>>(queries, W_q, Eq, 256);
    // EkT = exp(2*(W_k @ keys^T))   : M=256,  N=4096
    proj_exp_kernel<<<dim3(64, 4), 256, 0, stream>>>(W_k, keys, EkT, 4096);
    fused_attn_kernel<<<dim3(64, 16), 256, 0, stream>>>(Eq, EkT, w_v, values, out);
}

// Round 3
// 133.573 us; speedup vs baseline: 1.2188x; 1.1207x over previous
//
#include <hip/hip_runtime.h>

// B=16, Q=256, K=256, H=256, DV=256
#define Bn 16
#define Qn 256
#define Kn 256
#define Hn 256
#define DVn 256

constexpr float C2    = 2.8853900817779268f;   // 2/ln2 : e^{2x} = 2^(C2*x)
constexpr float LOG2E = 1.4426950408889634f;

__device__ __forceinline__ float fast_exp2(float x) { return __builtin_amdgcn_exp2f(x); }
__device__ __forceinline__ float fast_rcp(float x)  { return __builtin_amdgcn_rcpf(x); }

// ------------------------------------------------------------------
// K1 (combined): z=0: Eq = exp(2*(queries @ W_q^T))  [row-major 4096x256]
//                z=1: Ek = exp(2*(keys    @ W_k^T))  [interleaved b, h/4, k, 4]
// 64x64 tile, BK=16, 256 threads, 4x4 micro-tile, double-buffered LDS.
// grid (4, 64, 2) = 512 blocks.
// ------------------------------------------------------------------
__global__ __launch_bounds__(256)
void proj_exp_kernel(const float* __restrict__ q, const float* __restrict__ kx,
                     const float* __restrict__ wq, const float* __restrict__ wk,
                     float* __restrict__ Eq, float* __restrict__ Ek)
{
    const int z = blockIdx.z;
    const float* A = z ? kx : q;
    const float* W = z ? wk : wq;
    const int m0 = blockIdx.y * 64;
    const int n0 = blockIdx.x * 64;
    __shared__ __align__(16) float As[2][16][68];   // [buf][k][m]
    __shared__ __align__(16) float Bs[2][16][68];   // [buf][k][n]
    const int tid = threadIdx.x;
    const int tx = tid & 15, ty = tid >> 4;
    const int lr = tid >> 2, lk4 = (tid & 3) * 4;
    const float* Arow = A + (size_t)(m0 + lr) * Hn + lk4;
    const float* Wrow = W + (size_t)(n0 + lr) * Hn + lk4;
    {
        float4 a = *(const float4*)(Arow);
        float4 w = *(const float4*)(Wrow);
        As[0][lk4+0][lr] = a.x; As[0][lk4+1][lr] = a.y; As[0][lk4+2][lr] = a.z; As[0][lk4+3][lr] = a.w;
        Bs[0][lk4+0][lr] = w.x; Bs[0][lk4+1][lr] = w.y; Bs[0][lk4+2][lr] = w.z; Bs[0][lk4+3][lr] = w.w;
    }
    __syncthreads();
    float acc[4][4] = {};
    int cur = 0;
    for (int k0 = 0; k0 < Hn; k0 += 16) {
        float4 an, wn;
        const bool more = (k0 + 16 < Hn);
        if (more) {
            an = *(const float4*)(Arow + k0 + 16);
            wn = *(const float4*)(Wrow + k0 + 16);
        }
        #pragma unroll
        for (int kk = 0; kk < 16; ++kk) {
            float4 av = *(const float4*)&As[cur][kk][ty*4];
            float4 bv = *(const float4*)&Bs[cur][kk][tx*4];
            const float ar[4] = {av.x, av.y, av.z, av.w};
            const float br[4] = {bv.x, bv.y, bv.z, bv.w};
            #pragma unroll
            for (int i = 0; i < 4; ++i)
                #pragma unroll
                for (int j = 0; j < 4; ++j)
                    acc[i][j] = fmaf(ar[i], br[j], acc[i][j]);
        }
        if (more) {
            const int nxt = cur ^ 1;
            As[nxt][lk4+0][lr] = an.x; As[nxt][lk4+1][lr] = an.y; As[nxt][lk4+2][lr] = an.z; As[nxt][lk4+3][lr] = an.w;
            Bs[nxt][lk4+0][lr] = wn.x; Bs[nxt][lk4+1][lr] = wn.y; Bs[nxt][lk4+2][lr] = wn.z; Bs[nxt][lk4+3][lr] = wn.w;
            __syncthreads();
            cur = nxt;
        }
    }
    #pragma unroll
    for (int i = 0; i < 4; ++i) {
        float4 o;
        o.x = fast_exp2(C2 * acc[i][0]);
        o.y = fast_exp2(C2 * acc[i][1]);
        o.z = fast_exp2(C2 * acc[i][2]);
        o.w = fast_exp2(C2 * acc[i][3]);
        if (z == 0) {
            *(float4*)(Eq + (size_t)(m0 + ty*4 + i) * Hn + n0 + tx*4) = o;
        } else {
            const int m  = m0 + ty*4 + i;       // global key row = b*256 + k
            const int bq = m >> 8, kk2 = m & 255;
            const int h  = n0 + tx*4;
            *(float4*)(Ek + (size_t)bq * (Kn*Hn) + (size_t)(h >> 2) * (Kn*4) + kk2*4) = o;
        }
    }
}

// ------------------------------------------------------------------
// K2 fused: scores + softmax + PV -> out
// grid (Q/4=64, B=16), block 256. Thread t owns k-column t for 4 q-rows.
//   score(q,k) = -2 * sum_h wv[h] * rcp(1 + Eq[q,h]*Ek[k,h])  (softmax shift-inv)
// ek: 2x coalesced global b128 per 8-h chunk (interleaved layout)
// eq/wv: LDS same-address broadcast b128 (free)
// ------------------------------------------------------------------
__global__ __launch_bounds__(256)
void fused_attn_kernel(const float* __restrict__ Eq, const float* __restrict__ Ek,
                       const float* __restrict__ wv, const float* __restrict__ V,
                       float* __restrict__ out)
{
    const int b  = blockIdx.y;
    const int q0 = blockIdx.x * 4;
    __shared__ __align__(16) float sEq[4 * 256];
    __shared__ __align__(16) float swv[256];
    __shared__ __align__(16) float sP[4 * 260];
    __shared__ float sredM[4][4];
    __shared__ float sredS[4][4];
    const int tid = threadIdx.x;
    {
        const int q = tid >> 6, h4 = (tid & 63) * 4;
        float4 v = *(const float4*)(Eq + (size_t)(b*Qn + q0 + q) * Hn + h4);
        *(float4*)&sEq[q*256 + h4] = v;
        swv[tid] = wv[tid];
    }
    __syncthreads();

    float sc[4] = {0.f, 0.f, 0.f, 0.f};
    const float* ekp = Ek + (size_t)b * (Kn*Hn) + (size_t)tid * 4;  // [b][h/4][k][4]
    for (int hg = 0; hg < 64; hg += 2) {
        const float4 e0 = *(const float4*)(ekp + hg * (Kn*4));            // h0..h0+3
        const float4 e1 = *(const float4*)(ekp + hg * (Kn*4) + (Kn*4));   // h0+4..h0+7
        const int h0 = hg * 4;
        const float4 wa = *(const float4*)&swv[h0];
        const float4 wb = *(const float4*)&swv[h0 + 4];
        #pragma unroll
        for (int q = 0; q < 4; ++q) {
            const float4 ea = *(const float4*)&sEq[q*256 + h0];
            const float4 eb = *(const float4*)&sEq[q*256 + h0 + 4];
            float a = sc[q];
            a = fmaf(wa.x, fast_rcp(fmaf(ea.x, e0.x, 1.f)), a);
            a = fmaf(wa.y, fast_rcp(fmaf(ea.y, e0.y, 1.f)), a);
            a = fmaf(wa.z, fast_rcp(fmaf(ea.z, e0.z, 1.f)), a);
            a = fmaf(wa.w, fast_rcp(fmaf(ea.w, e0.w, 1.f)), a);
            a = fmaf(wb.x, fast_rcp(fmaf(eb.x, e1.x, 1.f)), a);
            a = fmaf(wb.y, fast_rcp(fmaf(eb.y, e1.y, 1.f)), a);
            a = fmaf(wb.z, fast_rcp(fmaf(eb.z, e1.z, 1.f)), a);
            a = fmaf(wb.w, fast_rcp(fmaf(eb.w, e1.w, 1.f)), a);
            sc[q] = a;
        }
    }

    // ---- softmax over k (scores = -2*sc), per-wave shuffle + cross-wave LDS ----
    const int w = tid >> 6, lane = tid & 63;
    #pragma unroll
    for (int q = 0; q < 4; ++q) {
        sc[q] = -2.0f * sc[q];
        float mx = sc[q];
        #pragma unroll
        for (int off = 32; off; off >>= 1) mx = fmaxf(mx, __shfl_xor(mx, off, 64));
        if (lane == 0) sredM[q][w] = mx;
    }
    __syncthreads();
    float p[4];
    #pragma unroll
    for (int q = 0; q < 4; ++q) {
        const float mx = fmaxf(fmaxf(sredM[q][0], sredM[q][1]),
                               fmaxf(sredM[q][2], sredM[q][3]));
        p[q] = fast_exp2(LOG2E * (sc[q] - mx));
        float s = p[q];
        #pragma unroll
        for (int off = 32; off; off >>= 1) s += __shfl_xor(s, off, 64);
        if (lane == 0) sredS[q][w] = s;
        sP[q*260 + tid] = p[q];
    }
    __syncthreads();
    float rinv[4];
    #pragma unroll
    for (int q = 0; q < 4; ++q)
        rinv[q] = fast_rcp(sredS[q][0] + sredS[q][1] + sredS[q][2] + sredS[q][3]);

    // ---- PV: thread owns dv = tid, all 4 q; p via LDS broadcast b128 ----
    float acc[4] = {0.f, 0.f, 0.f, 0.f};
    const float* Vb = V + (size_t)b * Kn * DVn + tid;
    for (int k = 0; k < Kn; k += 4) {
        float vv[4];
        #pragma unroll
        for (int j = 0; j < 4; ++j) vv[j] = Vb[(size_t)(k + j) * DVn];
        #pragma unroll
        for (int q = 0; q < 4; ++q) {
            const float4 pq = *(const float4*)&sP[q*260 + k];
            float a = acc[q];
            a = fmaf(pq.x, vv[0], a);
            a = fmaf(pq.y, vv[1], a);
            a = fmaf(pq.z, vv[2], a);
            a = fmaf(pq.w, vv[3], a);
            acc[q] = a;
        }
    }
    float* ob = out + (size_t)(b*Qn + q0) * DVn + tid;
    #pragma unroll
    for (int q = 0; q < 4; ++q)
        ob[(size_t)q * DVn] = acc[q] * rinv[q];
}

extern "C" void kernel_launch(void* const* d_in, const int* in_sizes, int n_in,
                              void* d_out, int out_size, void* d_ws, size_t ws_size,
                              hipStream_t stream) {
    const float* queries = (const float*)d_in[0];  // [16,256,256]
    const float* keys    = (const float*)d_in[1];  // [16,256,256]
    const float* values  = (const float*)d_in[2];  // [16,256,256]
    const float* W_q     = (const float*)d_in[3];  // [256,256]
    const float* W_k     = (const float*)d_in[4];  // [256,256]
    const float* w_v     = (const float*)d_in[5];  // [256]
    float* out = (float*)d_out;

    // workspace: Eq [4096][256] (4MB) | Ek interleaved [16][64][256][4] (4MB)
    float* Eq = (float*)d_ws;
    float* Ek = Eq + (size_t)Bn * Qn * Hn;

    proj_exp_kernel<<<dim3(4, 64, 2), 256, 0, stream>>>(queries, keys, W_q, W_k, Eq, Ek);
    fused_attn_kernel<<<dim3(64, 16), 256, 0, stream>>>(Eq, Ek, w_v, values, out);
}